// Round 1
// baseline (1560.637 us; speedup 1.0000x reference)
//
#include <hip/hip_runtime.h>
#include <hip/hip_bf16.h>
#include <math.h>

#define DD 512
#define LL 256
#define CC 128
#define ROWS 2048  // B*C = 16*128

typedef __attribute__((ext_vector_type(8))) __bf16 bf16x8;
typedef __attribute__((ext_vector_type(4))) float f32x4;

// ---------------- Kernel 1: masked mean over L ----------------
// E[row,:] = sum_l mask[row,l]*x[row,l,:] / max(sum_l mask[row,l], 1)
__global__ void k_masked_mean(const float* __restrict__ x, const float* __restrict__ mask,
                              float* __restrict__ E, __hip_bfloat16* __restrict__ Eb,
                              float* __restrict__ msum) {
    int row = blockIdx.x;
    int t = threadIdx.x;  // 0..255
    __shared__ float mlds[LL];
    __shared__ float red[256];
    __shared__ float4 comb[128];

    float mv = mask[(size_t)row * LL + t];
    mlds[t] = mv;
    red[t] = mv;
    __syncthreads();
    for (int s = 128; s > 0; s >>= 1) {
        if (t < s) red[t] += red[t + s];
        __syncthreads();
    }
    float total = red[0];
    float denom = 1.0f / fmaxf(total, 1.0f);
    if (t == 0) msum[row] = total;

    int c4 = t & 127;     // float4 column
    int half = t >> 7;    // 0 or 1
    const float4* x4 = (const float4*)(x + (size_t)row * LL * DD);
    float ax = 0, ay = 0, az = 0, aw = 0;
    for (int l = half; l < LL; l += 2) {
        float w = mlds[l];
        float4 v = x4[(size_t)l * 128 + c4];
        ax += w * v.x; ay += w * v.y; az += w * v.z; aw += w * v.w;
    }
    if (half) comb[c4] = make_float4(ax, ay, az, aw);
    __syncthreads();
    if (!half) {
        float4 o = comb[c4];
        ax = (ax + o.x) * denom;
        ay = (ay + o.y) * denom;
        az = (az + o.z) * denom;
        aw = (aw + o.w) * denom;
        ((float4*)(E + (size_t)row * DD))[c4] = make_float4(ax, ay, az, aw);
        __hip_bfloat16* eb = Eb + (size_t)row * DD + c4 * 4;
        eb[0] = __float2bfloat16(ax);
        eb[1] = __float2bfloat16(ay);
        eb[2] = __float2bfloat16(az);
        eb[3] = __float2bfloat16(aw);
    }
}

// ---------------- Kernel 2: transpose + cast to bf16 ----------------
// W: K x N (row-major f32)  ->  WT: N x K (row-major bf16)
__global__ void k_transpose_cast(const float* __restrict__ W, __hip_bfloat16* __restrict__ WT,
                                 int K, int N) {
    int idx = blockIdx.x * 256 + threadIdx.x;
    if (idx >= N * K) return;
    int n = idx / K;
    int k = idx - n * K;
    WT[idx] = __float2bfloat16(W[(size_t)k * N + n]);
}

// ---------------- Kernel 3: bf16 MFMA GEMM, C = A * BT^T + bias ----------------
// A: M x K bf16 row-major. BT: N x K bf16 row-major. Output f32 (GELU_BF16=0) or gelu->bf16 (=1).
// Block 256 = 4 waves; block computes 64x64 tile; wave w -> rows [w*16, w*16+16), 64 cols.
// MFMA 16x16x32 layouts (HW-verified): A: m=lane&15, k=quad*8+j; B: n=lane&15, k=quad*8+j;
// C/D: col=lane&15, row=quad*4+reg.
template <int GELU_BF16>
__global__ void k_gemm_bt(const __hip_bfloat16* __restrict__ A, const __hip_bfloat16* __restrict__ BT,
                          const float* __restrict__ bias, float* __restrict__ Cf,
                          __hip_bfloat16* __restrict__ Cb, int M, int N, int K) {
    int wave = threadIdx.x >> 6;
    int lane = threadIdx.x & 63;
    int m0 = blockIdx.y * 64 + wave * 16;
    int n0 = blockIdx.x * 64;
    int mrow = lane & 15;
    int quad = lane >> 4;

    const __bf16* Ab = (const __bf16*)A;
    const __bf16* Bb = (const __bf16*)BT;

    f32x4 acc0 = {0.f, 0.f, 0.f, 0.f};
    f32x4 acc1 = {0.f, 0.f, 0.f, 0.f};
    f32x4 acc2 = {0.f, 0.f, 0.f, 0.f};
    f32x4 acc3 = {0.f, 0.f, 0.f, 0.f};

    const __bf16* arow = Ab + (size_t)(m0 + mrow) * K + quad * 8;
    const __bf16* b0p = Bb + (size_t)(n0 + mrow) * K + quad * 8;
    const __bf16* b1p = b0p + (size_t)16 * K;
    const __bf16* b2p = b0p + (size_t)32 * K;
    const __bf16* b3p = b0p + (size_t)48 * K;

    for (int k0 = 0; k0 < K; k0 += 32) {
        bf16x8 a  = *(const bf16x8*)(arow + k0);
        bf16x8 b0 = *(const bf16x8*)(b0p + k0);
        bf16x8 b1 = *(const bf16x8*)(b1p + k0);
        bf16x8 b2 = *(const bf16x8*)(b2p + k0);
        bf16x8 b3 = *(const bf16x8*)(b3p + k0);
        acc0 = __builtin_amdgcn_mfma_f32_16x16x32_bf16(a, b0, acc0, 0, 0, 0);
        acc1 = __builtin_amdgcn_mfma_f32_16x16x32_bf16(a, b1, acc1, 0, 0, 0);
        acc2 = __builtin_amdgcn_mfma_f32_16x16x32_bf16(a, b2, acc2, 0, 0, 0);
        acc3 = __builtin_amdgcn_mfma_f32_16x16x32_bf16(a, b3, acc3, 0, 0, 0);
    }

    int col = lane & 15;
    int rbase = quad * 4;
    f32x4 accs[4] = {acc0, acc1, acc2, acc3};
#pragma unroll
    for (int tIdx = 0; tIdx < 4; tIdx++) {
#pragma unroll
        for (int r = 0; r < 4; r++) {
            int gr = m0 + rbase + r;
            int gc = n0 + tIdx * 16 + col;
            float v = accs[tIdx][r] + bias[gc];
            if (GELU_BF16) {
                v = 0.5f * v * (1.0f + erff(v * 0.70710678118654752f));
                Cb[(size_t)gr * N + gc] = __float2bfloat16(v);
            } else {
                Cf[(size_t)gr * N + gc] = v;
            }
        }
    }
}

// ---------------- Kernel 4: attention per (b,c) row ----------------
__global__ void k_attn(const float* __restrict__ qkv, const float* __restrict__ mask,
                       const float* __restrict__ msum, __hip_bfloat16* __restrict__ attnb) {
    int row = blockIdx.x;          // b*CC + c
    int b = row >> 7;
    int t = threadIdx.x;           // 0..255
    __shared__ float qs[DD];
    __shared__ float mc[LL];
    __shared__ float Sv[CC];
    __shared__ float red[256];

    const float* qrow = qkv + (size_t)row * 1536;
    qs[t] = qrow[t];
    qs[t + 256] = qrow[t + 256];
    mc[t] = mask[(size_t)row * LL + t];
    __syncthreads();

    int e = t >> 1;
    int h = t & 1;
    // q . k_e  (512 elems, split in halves of 256)
    const float4* k4 = (const float4*)(qkv + (size_t)(b * CC + e) * 1536 + 512);
    const float4* q4 = (const float4*)qs;
    float part = 0.0f;
#pragma unroll 8
    for (int i = 0; i < 64; i++) {
        float4 a = q4[h * 64 + i];
        float4 kk = k4[h * 64 + i];
        part += a.x * kk.x + a.y * kk.y + a.z * kk.z + a.w * kk.w;
    }
    // joint = mask_c . mask_e (256 elems, halves of 128)
    const float4* me4 = (const float4*)(mask + (size_t)(b * CC + e) * LL);
    const float4* mc4 = (const float4*)mc;
    float jpart = 0.0f;
#pragma unroll 8
    for (int i = 0; i < 32; i++) {
        float4 a = mc4[h * 32 + i];
        float4 mm = me4[h * 32 + i];
        jpart += a.x * mm.x + a.y * mm.y + a.z * mm.z + a.w * mm.w;
    }
    part += __shfl_xor(part, 1);
    jpart += __shfl_xor(jpart, 1);
    if (h == 0) {
        float tp = msum[row] + msum[b * CC + e];
        float overlap = 2.0f * jpart / fmaxf(tp, 1.0f);
        Sv[e] = part * 0.044194173824159216f * (0.5f + 0.5f * overlap);
    }
    __syncthreads();

    // softmax over 128 entries
    float v = (t < CC) ? Sv[t] : -INFINITY;
    red[t] = v;
    __syncthreads();
    for (int s = 128; s > 0; s >>= 1) {
        if (t < s) red[t] = fmaxf(red[t], red[t + s]);
        __syncthreads();
    }
    float mx = red[0];
    __syncthreads();
    float p = (t < CC) ? expf(v - mx) : 0.0f;
    red[t] = p;
    __syncthreads();
    for (int s = 128; s > 0; s >>= 1) {
        if (t < s) red[t] += red[t + s];
        __syncthreads();
    }
    float Z = red[0];
    __syncthreads();
    if (t < CC) Sv[t] = p / Z;
    __syncthreads();

    // attn_out[row, col] = sum_e A[e] * v[b,e,col]; cols t and t+256
    const float* vbase = qkv + (size_t)(b * CC) * 1536 + 1024;
    float a0 = 0.0f, a1 = 0.0f;
#pragma unroll 4
    for (int e2 = 0; e2 < CC; e2++) {
        float a = Sv[e2];
        a0 += a * vbase[(size_t)e2 * 1536 + t];
        a1 += a * vbase[(size_t)e2 * 1536 + t + 256];
    }
    attnb[(size_t)row * DD + t] = __float2bfloat16(a0);
    attnb[(size_t)row * DD + t + 256] = __float2bfloat16(a1);
}

// ---------------- Kernel 5: residual add + LayerNorm ----------------
template <int WRITE_BF16>
__global__ void k_add_ln(const float* __restrict__ X, const float* __restrict__ Y,
                         const float* __restrict__ g, const float* __restrict__ be,
                         float* __restrict__ Of, __hip_bfloat16* __restrict__ Ob) {
    int row = blockIdx.x;
    int t = threadIdx.x;  // 0..255, two elems per thread
    __shared__ float red[256];
    const float* xr = X + (size_t)row * DD;
    const float* yr = Y + (size_t)row * DD;
    float v0 = xr[t] + yr[t];
    float v1 = xr[t + 256] + yr[t + 256];
    red[t] = v0 + v1;
    __syncthreads();
    for (int s = 128; s > 0; s >>= 1) {
        if (t < s) red[t] += red[t + s];
        __syncthreads();
    }
    float mu = red[0] * (1.0f / 512.0f);
    __syncthreads();
    float d0 = v0 - mu, d1 = v1 - mu;
    red[t] = d0 * d0 + d1 * d1;
    __syncthreads();
    for (int s = 128; s > 0; s >>= 1) {
        if (t < s) red[t] += red[t + s];
        __syncthreads();
    }
    float var = red[0] * (1.0f / 512.0f);
    float rs = rsqrtf(var + 1e-5f);
    float o0 = d0 * rs * g[t] + be[t];
    float o1 = d1 * rs * g[t + 256] + be[t + 256];
    Of[(size_t)row * DD + t] = o0;
    Of[(size_t)row * DD + t + 256] = o1;
    if (WRITE_BF16) {
        Ob[(size_t)row * DD + t] = __float2bfloat16(o0);
        Ob[(size_t)row * DD + t + 256] = __float2bfloat16(o1);
    }
}

extern "C" void kernel_launch(void* const* d_in, const int* in_sizes, int n_in,
                              void* d_out, int out_size, void* d_ws, size_t ws_size,
                              hipStream_t stream) {
    const float* x    = (const float*)d_in[0];
    const float* mask = (const float*)d_in[1];
    const float* Wqkv = (const float*)d_in[2];
    const float* bqkv = (const float*)d_in[3];
    const float* Wo   = (const float*)d_in[4];
    const float* bo   = (const float*)d_in[5];
    const float* W1   = (const float*)d_in[6];
    const float* b1   = (const float*)d_in[7];
    const float* W2   = (const float*)d_in[8];
    const float* b2   = (const float*)d_in[9];
    const float* g1   = (const float*)d_in[10];
    const float* be1  = (const float*)d_in[11];
    const float* g2   = (const float*)d_in[12];
    const float* be2  = (const float*)d_in[13];
    float* out = (float*)d_out;

    char* ws = (char*)d_ws;
    size_t off = 0;
    auto alloc = [&](size_t bytes) -> void* {
        void* p = ws + off;
        off = (off + bytes + 255) & ~(size_t)255;
        return p;
    };
    float* E            = (float*)alloc((size_t)ROWS * DD * 4);
    __hip_bfloat16* Eb  = (__hip_bfloat16*)alloc((size_t)ROWS * DD * 2);
    float* msum         = (float*)alloc((size_t)ROWS * 4);
    float* qkv          = (float*)alloc((size_t)ROWS * 1536 * 4);
    __hip_bfloat16* WqkvT = (__hip_bfloat16*)alloc((size_t)1536 * 512 * 2);
    __hip_bfloat16* WoT   = (__hip_bfloat16*)alloc((size_t)512 * 512 * 2);
    __hip_bfloat16* W1T   = (__hip_bfloat16*)alloc((size_t)1024 * 512 * 2);
    __hip_bfloat16* W2T   = (__hip_bfloat16*)alloc((size_t)512 * 1024 * 2);
    __hip_bfloat16* attnb = (__hip_bfloat16*)alloc((size_t)ROWS * DD * 2);
    float* o            = (float*)alloc((size_t)ROWS * DD * 4);
    float* E2           = (float*)alloc((size_t)ROWS * DD * 4);
    __hip_bfloat16* E2b = (__hip_bfloat16*)alloc((size_t)ROWS * DD * 2);
    __hip_bfloat16* hb  = (__hip_bfloat16*)alloc((size_t)ROWS * 1024 * 2);
    float* h2           = (float*)alloc((size_t)ROWS * DD * 4);

    // 1. masked mean
    k_masked_mean<<<ROWS, 256, 0, stream>>>(x, mask, E, Eb, msum);
    // 2. weight transpose+cast
    k_transpose_cast<<<(1536 * 512 + 255) / 256, 256, 0, stream>>>(Wqkv, WqkvT, 512, 1536);
    k_transpose_cast<<<(512 * 512 + 255) / 256, 256, 0, stream>>>(Wo, WoT, 512, 512);
    k_transpose_cast<<<(512 * 1024 + 255) / 256, 256, 0, stream>>>(W1, W1T, 512, 1024);
    k_transpose_cast<<<(1024 * 512 + 255) / 256, 256, 0, stream>>>(W2, W2T, 1024, 512);
    // 3. qkv = E @ Wqkv + bqkv
    k_gemm_bt<0><<<dim3(1536 / 64, ROWS / 64), 256, 0, stream>>>(Eb, WqkvT, bqkv, qkv, nullptr, ROWS, 1536, 512);
    // 4. attention (scores, overlap, softmax, A@v)
    k_attn<<<ROWS, 256, 0, stream>>>(qkv, mask, msum, attnb);
    // 5. o = attn @ Wo + bo
    k_gemm_bt<0><<<dim3(512 / 64, ROWS / 64), 256, 0, stream>>>(attnb, WoT, bo, o, nullptr, ROWS, 512, 512);
    // 6. E2 = LN(E + o)
    k_add_ln<1><<<ROWS, 256, 0, stream>>>(E, o, g1, be1, E2, E2b);
    // 7. h = gelu(E2 @ W1 + b1) -> bf16
    k_gemm_bt<1><<<dim3(1024 / 64, ROWS / 64), 256, 0, stream>>>(E2b, W1T, b1, nullptr, hb, ROWS, 1024, 512);
    // 8. h2 = h @ W2 + b2
    k_gemm_bt<0><<<dim3(512 / 64, ROWS / 64), 256, 0, stream>>>(hb, W2T, b2, h2, nullptr, ROWS, 512, 1024);
    // 9. out = LN(E2 + h2)
    k_add_ln<0><<<ROWS, 256, 0, stream>>>(E2, h2, g2, be2, out, nullptr);
}